// Round 10
// baseline (46.159 us; speedup 1.0000x reference)
//
#include <hip/hip_runtime.h>
#include <hip/hip_bf16.h>

#define NV 16384
#define NT 256
#define NTILES 512                  // 32-point MFMA tiles per mesh
#define NCH 16                      // ref chunks per direction
#define CHT (NTILES / NCH)          // 32 rtiles per chunk
#define QPW 2                       // query tiles per wave
#define NN_BX (NTILES / (4 * QPW))  // 64 blocks in x (4 waves/block)
#define RES_QPW 4                   // queries per wave (resolve)
#define RES_QPB 16                  // per block
#define RES_BLOCKS (NV / RES_QPB)   // 1024 per direction
#define NPART (2 * RES_BLOCKS)      // 2048 partials

typedef __attribute__((ext_vector_type(8))) short bf16x8;
typedef __attribute__((ext_vector_type(16))) float f32x16;

__device__ __forceinline__ short bf16bits(float f) {
    __hip_bfloat16 h = __float2bfloat16(f);
    return *reinterpret_cast<short*>(&h);
}
__device__ __forceinline__ float bf16tof(short s) {
    __hip_bfloat16 h = *reinterpret_cast<__hip_bfloat16*>(&s);
    return __bfloat162float(h);
}
__device__ __forceinline__ unsigned sortable(float f) {
    unsigned u = __float_as_uint(f);
    return (u & 0x80000000u) ? ~u : (u | 0x80000000u);
}
__device__ __forceinline__ float min3f(float a, float b, float c) {
    float r;
    asm("v_min3_f32 %0, %1, %2, %3" : "=v"(r) : "v"(a), "v"(b), "v"(c));
    return r;
}
// min over the 16 f32 of one MFMA accumulator (in-lane), 8 ops, depth 3
__device__ __forceinline__ float tree16(const f32x16& c) {
    float t0 = min3f(c[0], c[1], c[2]);
    float t1 = min3f(c[3], c[4], c[5]);
    float t2 = min3f(c[6], c[7], c[8]);
    float t3 = min3f(c[9], c[10], c[11]);
    float t4 = min3f(c[12], c[13], c[14]);
    float s0 = min3f(t0, t1, c[15]);
    float s1 = min3f(t2, t3, t4);
    return fminf(s0, s1);
}

// MFMA with VGPR-forced D and C (inline asm): avoids the builtin's AGPR
// accumulator (16 v_accvgpr_write + 16 v_accvgpr_read per MFMA = the ~6x
// VALU inflation measured in R8). zc (16 zero VGPRs) is reused by every call.
__device__ __forceinline__ f32x16 mfma_tile(bf16x8 a, bf16x8 b, f32x16 zc) {
    f32x16 d;
    asm("v_mfma_f32_32x32x16_bf16 %0, %1, %2, %3"
        : "=&v"(d) : "v"(a), "v"(b), "v"(zc));
    return d;
}

// Fragment packing (K=11 of 16). Metric m(ref,query) = 0.5*||r||^2 - q.r:
//   A(ref) k:   [rh.x rh.y rh.z | rl.x rl.y rl.z | rh.x rh.y || rh.z nh nl | 0..]
//   B(query) k: [-qh.x -qh.y -qh.z | -qh.x -qh.y -qh.z | -ql.x -ql.y || -ql.z 1 1 | 0..]
// vh = bf16(v), vl = bf16(v - f32(vh)), n = 0.5||r||^2 split nh+nl.
// A and B share the (half,elem)->k mapping so any permutation cancels.
__device__ __forceinline__ bf16x8 make_a(float x, float y, float z, int half) {
    short hx = bf16bits(x), hy = bf16bits(y), hz = bf16bits(z);
    short lx = bf16bits(x - bf16tof(hx));
    short ly = bf16bits(y - bf16tof(hy));
    short lz = bf16bits(z - bf16tof(hz));
    float n  = 0.5f * fmaf(z, z, fmaf(y, y, x * x));
    short nh = bf16bits(n);
    short nl = bf16bits(n - bf16tof(nh));
    bf16x8 v;
    v[0] = half ? hz : hx;  v[1] = half ? nh : hy;
    v[2] = half ? nl : hz;  v[3] = half ? (short)0 : lx;
    v[4] = half ? (short)0 : ly;  v[5] = half ? (short)0 : lz;
    v[6] = half ? (short)0 : hx;  v[7] = half ? (short)0 : hy;
    return v;
}
__device__ __forceinline__ bf16x8 make_b(float x, float y, float z, int half) {
    short hx = bf16bits(x), hy = bf16bits(y), hz = bf16bits(z);
    short nhx = bf16bits(-x), nhy = bf16bits(-y), nhz = bf16bits(-z);
    short nlx = bf16bits(bf16tof(hx) - x);
    short nly = bf16bits(bf16tof(hy) - y);
    short nlz = bf16bits(bf16tof(hz) - z);
    const short one = 0x3F80;
    bf16x8 v;
    v[0] = half ? nlz : nhx;  v[1] = half ? one : nhy;
    v[2] = half ? one : nhz;  v[3] = half ? (short)0 : nhx;
    v[4] = half ? (short)0 : nhy;  v[5] = half ? (short)0 : nhz;
    v[6] = half ? (short)0 : nlx;  v[7] = half ? (short)0 : nly;
    return v;
}

// Pack all A (ref-side) fragments once. 1 MB, L2-resident.
__global__ __launch_bounds__(NT) void prep_kernel(
    const float* __restrict__ pred_v, const float* __restrict__ trg_v,
    short* __restrict__ Apack)
{
    int gid = blockIdx.x * NT + threadIdx.x;  // 0..65535
    int d   = gid >> 15;
    int rem = gid & 32767;
    int t   = rem >> 6;
    int l   = rem & 63;
    const float* rpts = d ? trg_v : pred_v;   // refs for dir d
    int p = t * 32 + (l & 31);
    bf16x8 v = make_a(rpts[3 * p + 0], rpts[3 * p + 1], rpts[3 * p + 2], l >> 5);
    *(bf16x8*)(Apack + ((size_t)gid) * 8) = v;
}

// one rtile step: 2 asm-MFMAs + min3 trees + (dmin, tile) tracking
#define STEP(areg, tle)                                            \
    {                                                              \
        f32x16 d0 = mfma_tile(areg, b0, zc);                       \
        float m0 = tree16(d0);                                     \
        bool l0 = m0 < dmin0;                                      \
        dmin0 = l0 ? m0 : dmin0;                                   \
        bp0 = l0 ? (tle) : bp0;                                    \
        f32x16 d1 = mfma_tile(areg, b1, zc);                       \
        float m1 = tree16(d1);                                     \
        bool l1 = m1 < dmin1;                                      \
        dmin1 = l1 ? m1 : dmin1;                                   \
        bp1 = l1 ? (tle) : bp1;                                    \
    }

// Pass 1: MFMA all-pairs min, no LDS, no barriers. Wave: 2 qtiles x one
// 32-rtile chunk. 8192 waves (8/SIMD) + 4-deep named-register prefetch
// (static indexing, rule-#20-safe) keep ~32 L2 loads in flight per SIMD ->
// L2 latency hidden. Cross-half shfl merge; per-chunk key store.
__global__ __launch_bounds__(NT) void nn_mfma_kernel(
    const float* __restrict__ pred_v, const float* __restrict__ trg_v,
    const short* __restrict__ Apack, unsigned long long* __restrict__ results)
{
    const int tid = threadIdx.x, lane = tid & 63, w = tid >> 6;
    const int dir = blockIdx.z, ch = blockIdx.y;
    const float* qpts = dir ? pred_v : trg_v;
    const int qt0 = (blockIdx.x * 4 + w) * QPW;
    const int half = lane >> 5;
    const bf16x8* Avec = (const bf16x8*)Apack + (size_t)dir * NTILES * 64;

    const int qp0 = qt0 * 32 + (lane & 31);
    bf16x8 b0 = make_b(qpts[3 * qp0 + 0], qpts[3 * qp0 + 1], qpts[3 * qp0 + 2], half);
    bf16x8 b1 = make_b(qpts[3 * (qp0 + 32) + 0], qpts[3 * (qp0 + 32) + 1],
                       qpts[3 * (qp0 + 32) + 2], half);

    f32x16 zc = {};   // 16 zero VGPRs, init once, C-operand of every MFMA
    float dmin0 = 1e30f, dmin1 = 1e30f;
    int bp0 = 0, bp1 = 0;

    const bf16x8* ap = Avec + (size_t)(ch * CHT) * 64 + lane;
    bf16x8 a0 = ap[0 * 64], a1 = ap[1 * 64], a2 = ap[2 * 64], a3 = ap[3 * 64];

    const int tbase = ch * CHT;
#pragma unroll
    for (int t = 0; t < CHT - 4; t += 4) {
        STEP(a0, tbase + t + 0); a0 = ap[(t + 4) * 64];
        STEP(a1, tbase + t + 1); a1 = ap[(t + 5) * 64];
        STEP(a2, tbase + t + 2); a2 = ap[(t + 6) * 64];
        STEP(a3, tbase + t + 3); a3 = ap[(t + 7) * 64];
    }
    STEP(a0, tbase + CHT - 4);
    STEP(a1, tbase + CHT - 3);
    STEP(a2, tbase + CHT - 2);
    STEP(a3, tbase + CHT - 1);

    unsigned long long k0 = ((unsigned long long)sortable(dmin0) << 32) | (unsigned)bp0;
    unsigned long long k1 = ((unsigned long long)sortable(dmin1) << 32) | (unsigned)bp1;
    { unsigned long long o = __shfl_xor(k0, 32); k0 = (o < k0) ? o : k0; }
    { unsigned long long o = __shfl_xor(k1, 32); k1 = (o < k1) ? o : k1; }
    if (lane < 32) {
        size_t base = ((size_t)dir * NCH + ch) * NV;
        results[base + qt0 * 32 + lane] = k0;
        results[base + (qt0 + 1) * 32 + lane] = k1;
    }
}

// Pass 2 + loss (fence-free). Per query: min over 16 chunk keys (lowest
// tile wins ties), exact fp32 rescan of the winning 32-point tile (lanes
// 32-63 duplicate; packed-u64 lane-min -> first-occurrence argmin), lane 0
// accumulates MSE; deterministic block reduce to partials.
__global__ __launch_bounds__(NT) void resolve_loss_kernel(
    const float* __restrict__ pred_v, const float* __restrict__ trg_v,
    const float* __restrict__ pred_e, const float* __restrict__ trg_e,
    const unsigned long long* __restrict__ results, float* __restrict__ partials)
{
    const int dir = blockIdx.y;
    const float* qpts = dir ? pred_v : trg_v;
    const float* rpts = dir ? trg_v : pred_v;
    const float* qe_b = dir ? pred_e : trg_e;
    const float* re_b = dir ? trg_e : pred_e;

    const int tid = threadIdx.x, lane = tid & 63, wv = tid >> 6;
    float acc = 0.0f;

    for (int qq = 0; qq < RES_QPW; qq++) {
        const int q = blockIdx.x * RES_QPB + wv * RES_QPW + qq;

        unsigned long long key = 0xFFFFFFFFFFFFFFFFULL;
        if (lane < NCH)
            key = results[((size_t)dir * NCH + lane) * NV + q];
        unsigned long long o;
        o = __shfl_xor(key, 8); key = (o < key) ? o : key;
        o = __shfl_xor(key, 4); key = (o < key) ? o : key;
        o = __shfl_xor(key, 2); key = (o < key) ? o : key;
        o = __shfl_xor(key, 1); key = (o < key) ? o : key;
        key = __shfl(key, 0);
        const int tile = (int)(unsigned)(key & 0xFFFFFFFFULL);
        const int i = tile * 32 + (lane & 31);   // lanes 32-63 duplicate

        float nqx = -qpts[3 * q + 0], nqy = -qpts[3 * q + 1], nqz = -qpts[3 * q + 2];
        float x = rpts[3 * i + 0], y = rpts[3 * i + 1], z = rpts[3 * i + 2];
        float rw = 0.5f * fmaf(z, z, fmaf(y, y, x * x));
        float s = fmaf(nqx, x, rw);
        s = fmaf(nqy, y, s);
        s = fmaf(nqz, z, s);

        unsigned long long kk = ((unsigned long long)sortable(s) << 32) | (unsigned)i;
#pragma unroll
        for (int off = 32; off > 0; off >>= 1) {
            unsigned long long t = __shfl_xor(kk, off);
            kk = (t < kk) ? t : kk;
        }
        if (lane == 0) {
            int j = (int)(unsigned)(kk & 0xFFFFFFFFULL);
            float dx = qe_b[3 * q + 0] - re_b[3 * j + 0];
            float dy = qe_b[3 * q + 1] - re_b[3 * j + 1];
            float dz = qe_b[3 * q + 2] - re_b[3 * j + 2];
            acc += fmaf(dx, dx, fmaf(dy, dy, dz * dz));
        }
    }

    __shared__ float wsum[4];
    if (lane == 0) wsum[wv] = acc;
    __syncthreads();
    if (tid == 0)
        partials[dir * RES_BLOCKS + blockIdx.x] =
            (wsum[0] + wsum[1]) + (wsum[2] + wsum[3]);
}

__global__ __launch_bounds__(NT) void final_kernel(
    const float* __restrict__ partials, float* __restrict__ out)
{
    const int tid = threadIdx.x;
    float acc = 0.0f;
#pragma unroll
    for (int t = 0; t < NPART / NT; t++) acc += partials[t * NT + tid];
    __shared__ float red[NT];
    red[tid] = acc;
    __syncthreads();
    for (int s = NT / 2; s > 0; s >>= 1) {
        if (tid < s) red[tid] += red[tid + s];
        __syncthreads();
    }
    if (tid == 0) out[0] = red[0] * (1.0f / 49152.0f);  // both losses: mean over V*3
}

extern "C" void kernel_launch(void* const* d_in, const int* in_sizes, int n_in,
                              void* d_out, int out_size, void* d_ws, size_t ws_size,
                              hipStream_t stream) {
    const float* pred_v = (const float*)d_in[0];
    const float* trg_v  = (const float*)d_in[1];
    const float* pred_e = (const float*)d_in[2];
    const float* trg_e  = (const float*)d_in[3];
    float* out = (float*)d_out;

    unsigned long long* results = (unsigned long long*)d_ws;  // 2*16*NV u64 = 4 MB
    short* Apack = (short*)(results + 2 * NCH * NV);          // 1 MB
    float* partials = (float*)(Apack + 2 * NTILES * 512);     // 8 KB

    prep_kernel<<<(2 * NTILES * 64) / NT, NT, 0, stream>>>(pred_v, trg_v, Apack);

    nn_mfma_kernel<<<dim3(NN_BX, NCH, 2), NT, 0, stream>>>(
        pred_v, trg_v, Apack, results);

    resolve_loss_kernel<<<dim3(RES_BLOCKS, 2), NT, 0, stream>>>(
        pred_v, trg_v, pred_e, trg_e, results, partials);

    final_kernel<<<1, NT, 0, stream>>>(partials, out);
}